// Round 1
// baseline (305.866 us; speedup 1.0000x reference)
//
#include <hip/hip_runtime.h>
#include <hip/hip_bf16.h>
#include <hip/hip_fp16.h>
#include <type_traits>

typedef _Float16 f16;
typedef __attribute__((ext_vector_type(8))) _Float16 f16x8;
typedef __attribute__((ext_vector_type(4))) float floatx4;

#define B_ 4
#define T_ 2048
#define D_ 1024

// ws layout (bytes); total need = 106,954,752
#define XB_OFF   0ul          // f16 x: 8192*1024*2 = 16 MB ; reused as Vt after QKV GEMM
#define WB_OFF   16777216ul   // f16 W concat (3072x1024): 6 MB
#define QKV_OFF  23068672ul   // f16 qkv (8192x3072): 48 MB
#define S_OFF    73400320ul   // f16 S (4x2048x2048): 32 MB
#define VT_OFF   0ul          // f16 Vt (4x1024x2048): 16 MB (overwrites xb)

// ---------------- cast fp32 -> fp16 (x and the three W's) ----------------
__global__ __launch_bounds__(256) void cast_all(
    const float* __restrict__ x, const float* __restrict__ wq,
    const float* __restrict__ wk, const float* __restrict__ wv,
    f16* __restrict__ xb, f16* __restrict__ wb)
{
    long i = (long)blockIdx.x * 256 + threadIdx.x;   // group-of-4 index
    const float4* src; f16* dst;
    if (i < 2097152L)            { src = (const float4*)x;  dst = xb; }
    else if (i < 2359296L)       { i -= 2097152L; src = (const float4*)wq; dst = wb; }
    else if (i < 2621440L)       { i -= 2359296L; src = (const float4*)wk; dst = wb + 1048576; }
    else                         { i -= 2621440L; src = (const float4*)wv; dst = wb + 2097152; }
    float4 v = src[i];
    union { f16 h[4]; uint2 u; } o;
    o.h[0] = (f16)v.x; o.h[1] = (f16)v.y; o.h[2] = (f16)v.z; o.h[3] = (f16)v.w;
    ((uint2*)dst)[i] = o.u;
}

// ---------------- NT GEMM: C[m,n] = alpha * sum_k A[m,k]*B[n,k] ----------------
// 128x128 tile, BK=32, 4 waves (2x2), each wave 64x64 = 4x4 MFMA 16x16x32 tiles.
template <typename CT>
__global__ __launch_bounds__(256) void gemm_nt(
    const f16* __restrict__ A, int lda, long sA,
    const f16* __restrict__ B, int ldb, long sB,
    CT* __restrict__ C, int ldc, long sC,
    int K, float alpha)
{
    __shared__ f16 As[128 * 32];
    __shared__ f16 Bs[128 * 32];

    const int tid = threadIdx.x;
    const int m0 = blockIdx.y * 128;
    const int n0 = blockIdx.x * 128;
    const int bz = blockIdx.z;
    A += (long)bz * sA;
    B += (long)bz * sB;
    C += (long)bz * sC;

    const int w  = tid >> 6;
    const int l  = tid & 63;
    const int wm = (w >> 1) * 64;
    const int wn = (w & 1) * 64;
    const int lr = l & 15;    // A: m within 16-tile ; B: n within 16-tile
    const int kg = l >> 4;    // k-group: holds k = kg*8 .. kg*8+7

    // staging: thread covers 8 contiguous elems; 2 chunks of 64 rows each
    const int srow = tid >> 2;         // 0..63
    const int scol = (tid & 3) * 8;    // 0/8/16/24

    floatx4 acc[4][4] = {};

    const long ldaL = lda, ldbL = ldb;
    const f16* Aptr = A + (long)(m0 + srow) * ldaL + scol;
    const f16* Bptr = B + (long)(n0 + srow) * ldbL + scol;
    f16* Asw = &As[srow * 32 + scol];
    f16* Bsw = &Bs[srow * 32 + scol];

    for (int k0 = 0; k0 < K; k0 += 32) {
        uint4 a0 = *(const uint4*)(Aptr);
        uint4 a1 = *(const uint4*)(Aptr + 64 * ldaL);
        uint4 b0 = *(const uint4*)(Bptr);
        uint4 b1 = *(const uint4*)(Bptr + 64 * ldbL);
        __syncthreads();
        *(uint4*)(Asw)           = a0;
        *(uint4*)(Asw + 64 * 32) = a1;
        *(uint4*)(Bsw)           = b0;
        *(uint4*)(Bsw + 64 * 32) = b1;
        __syncthreads();

        f16x8 af[4], bf[4];
        #pragma unroll
        for (int mi = 0; mi < 4; mi++)
            af[mi] = *(const f16x8*)&As[(wm + mi * 16 + lr) * 32 + kg * 8];
        #pragma unroll
        for (int ni = 0; ni < 4; ni++)
            bf[ni] = *(const f16x8*)&Bs[(wn + ni * 16 + lr) * 32 + kg * 8];
        #pragma unroll
        for (int mi = 0; mi < 4; mi++)
            #pragma unroll
            for (int ni = 0; ni < 4; ni++)
                acc[mi][ni] = __builtin_amdgcn_mfma_f32_16x16x32_f16(af[mi], bf[ni], acc[mi][ni], 0, 0, 0);

        Aptr += 32; Bptr += 32;
    }

    // epilogue: C/D layout (measured m89/m91): col = lane&15, row = (lane>>4)*4 + reg
    #pragma unroll
    for (int mi = 0; mi < 4; mi++) {
        #pragma unroll
        for (int ni = 0; ni < 4; ni++) {
            #pragma unroll
            for (int r = 0; r < 4; r++) {
                int row = m0 + wm + mi * 16 + kg * 4 + r;
                int col = n0 + wn + ni * 16 + lr;
                float v = acc[mi][ni][r] * alpha;
                if constexpr (std::is_same<CT, float>::value)
                    C[(long)row * ldc + col] = v;
                else
                    C[(long)row * ldc + col] = (f16)v;
            }
        }
    }
}

// ---------------- transpose V (within qkv) -> Vt[b][d][j] ----------------
__global__ __launch_bounds__(256) void transpose_v(const f16* __restrict__ qkv, f16* __restrict__ vt)
{
    __shared__ f16 tile[32][33];
    int b  = blockIdx.z;
    int j0 = blockIdx.x * 32;
    int d0 = blockIdx.y * 32;
    int tx = threadIdx.x & 31;
    int ty = threadIdx.x >> 5;   // 0..7
    #pragma unroll
    for (int i = 0; i < 4; i++) {
        int j = j0 + ty + i * 8;
        tile[ty + i * 8][tx] = qkv[((long)b * T_ + j) * 3072 + 2048 + d0 + tx];
    }
    __syncthreads();
    #pragma unroll
    for (int i = 0; i < 4; i++) {
        int d = d0 + ty + i * 8;
        vt[((long)b * D_ + d) * T_ + j0 + tx] = tile[tx][ty + i * 8];
    }
}

// ---------------- in-place row softmax over 2048 fp16 logits ----------------
__global__ __launch_bounds__(256) void softmax_rows(f16* __restrict__ S)
{
    long row = blockIdx.x;
    f16* p = S + row * 2048;
    union { uint4 u; f16 h[8]; } d;
    d.u = ((const uint4*)p)[threadIdx.x];
    float v[8];
    float mx = -1e30f;
    #pragma unroll
    for (int i = 0; i < 8; i++) { v[i] = (float)d.h[i]; mx = fmaxf(mx, v[i]); }
    #pragma unroll
    for (int off = 32; off; off >>= 1) mx = fmaxf(mx, __shfl_xor(mx, off, 64));
    __shared__ float redm[4];
    __shared__ float reds[4];
    int w = threadIdx.x >> 6, l = threadIdx.x & 63;
    if (l == 0) redm[w] = mx;
    __syncthreads();
    mx = fmaxf(fmaxf(redm[0], redm[1]), fmaxf(redm[2], redm[3]));
    float s = 0.f;
    #pragma unroll
    for (int i = 0; i < 8; i++) { v[i] = __expf(v[i] - mx); s += v[i]; }
    #pragma unroll
    for (int off = 32; off; off >>= 1) s += __shfl_xor(s, off, 64);
    if (l == 0) reds[w] = s;
    __syncthreads();
    s = reds[0] + reds[1] + reds[2] + reds[3];
    float inv = 1.f / s;
    #pragma unroll
    for (int i = 0; i < 8; i++) d.h[i] = (f16)(v[i] * inv);
    ((uint4*)p)[threadIdx.x] = d.u;
}

// ---------------- launch ----------------
extern "C" void kernel_launch(void* const* d_in, const int* in_sizes, int n_in,
                              void* d_out, int out_size, void* d_ws, size_t ws_size,
                              hipStream_t stream)
{
    const float* x  = (const float*)d_in[0];
    const float* wq = (const float*)d_in[1];
    const float* wk = (const float*)d_in[2];
    const float* wv = (const float*)d_in[3];
    float* out = (float*)d_out;
    char* ws = (char*)d_ws;
    f16* xb  = (f16*)(ws + XB_OFF);
    f16* wb  = (f16*)(ws + WB_OFF);
    f16* qkv = (f16*)(ws + QKV_OFF);
    f16* s   = (f16*)(ws + S_OFF);
    f16* vt  = (f16*)(ws + VT_OFF);

    // 1) cast x, Wq, Wk, Wv to fp16 (Wb = [Wq;Wk;Wv] as 3072x1024)
    cast_all<<<11264, 256, 0, stream>>>(x, wq, wk, wv, xb, wb);

    // 2) QKV = xb @ Wb^T : M=8192, N=3072, K=1024, fp16 out
    gemm_nt<f16><<<dim3(24, 64, 1), 256, 0, stream>>>(
        xb, 1024, 0L, wb, 1024, 0L, qkv, 3072, 0L, 1024, 1.0f);

    // 3) Vt[b][d][j] = V[b][j][d]
    transpose_v<<<dim3(64, 32, 4), 256, 0, stream>>>(qkv, vt);

    // 4) S = (1/32) * Q @ K^T per batch : M=N=2048, K=1024
    gemm_nt<f16><<<dim3(16, 16, 4), 256, 0, stream>>>(
        qkv,        3072, (long)T_ * 3072,
        qkv + 1024, 3072, (long)T_ * 3072,
        s,          2048, (long)T_ * 2048, 1024, 0.03125f);

    // 5) softmax rows, in place
    softmax_rows<<<8192, 256, 0, stream>>>(s);

    // 6) O = P @ Vt^T per batch : M=2048, N=1024, K=2048, fp32 out -> d_out
    gemm_nt<float><<<dim3(8, 16, 4), 256, 0, stream>>>(
        s,  2048, (long)T_ * 2048,
        vt, 2048, (long)D_ * 2048,
        out, 1024, (long)T_ * 1024, 2048, 1.0f);
}